// Round 1
// baseline (62905.713 us; speedup 1.0000x reference)
//
#include <hip/hip_runtime.h>

#define SEQ   2048
#define BATCH 128
#define IN    64
#define HID   256
#define OUTD  64
#define G4    1024  // 4*HID

__device__ __forceinline__ float fexp2(float v) { return __builtin_amdgcn_exp2f(v); }
__device__ __forceinline__ float frcp(float v)  { return __builtin_amdgcn_rcpf(v); }
// sigmoid(x) = 1/(1+exp(-x)) ; exp(-x) = exp2(-x*log2(e))
__device__ __forceinline__ float fsig(float v)  { return frcp(1.0f + fexp2(v * -1.44269504088896f)); }
// tanh(x) = 1 - 2/(exp(2x)+1)
__device__ __forceinline__ float ftanh(float v) { return 1.0f - 2.0f * frcp(1.0f + fexp2(v * 2.88539008177793f)); }

// One workgroup per batch element. Thread t (0..1023) owns gate-row t:
// W_hh[t][0:256] + W_ih[t][0:64] in registers. h, x, lin live in LDS.
// Readout fused: thread t computes partial for output o=t>>4 over h-chunk (t&15).
__global__ __launch_bounds__(1024, 4) void lstm_persistent(
    const float* __restrict__ x,      // (SEQ,B,I)
    const float* __restrict__ h0,     // (B,H)
    const float* __restrict__ c0,     // (B,H)
    const float* __restrict__ W_ih,   // (4H,I)
    const float* __restrict__ W_hh,   // (4H,H)
    const float* __restrict__ bias,   // (4H)
    const float* __restrict__ W_out,  // (O,H)
    const float* __restrict__ b_out,  // (O)
    float* __restrict__ out)          // (SEQ,B,O)
{
    const int b = blockIdx.x;
    const int t = threadIdx.x;

    __shared__ __align__(16) float h_sh[HID];
    __shared__ __align__(16) float lin_sh[G4];
    __shared__ __align__(16) float x_sh[2][IN];

    // ---- load persistent weights into registers ----
    float4 wh[HID / 4];
    {
        const float4* p = (const float4*)(W_hh + (size_t)t * HID);
        #pragma unroll
        for (int k = 0; k < HID / 4; ++k) wh[k] = p[k];
    }
    float4 wi[IN / 4];
    {
        const float4* p = (const float4*)(W_ih + (size_t)t * IN);
        #pragma unroll
        for (int k = 0; k < IN / 4; ++k) wi[k] = p[k];
    }
    const int o   = t >> 4;
    const int seg = t & 15;
    float4 wo[4];
    {
        const float4* p = (const float4*)(W_out + (size_t)o * HID + seg * 16);
        #pragma unroll
        for (int q = 0; q < 4; ++q) wo[q] = p[q];
    }
    const float bias_t = bias[t];
    const float bo     = b_out[o];

    // ---- state init ----
    float c = 0.0f;
    if (t < HID) {
        h_sh[t] = h0[(size_t)b * HID + t];
        c       = c0[(size_t)b * HID + t];
    }
    if (t < IN) x_sh[0][t] = x[(size_t)b * IN + t];
    __syncthreads();

    int p = 0;
    for (int s = 0; s < SEQ; ++s) {
        // prefetch next timestep's x (hidden under the FMA block)
        float xnext = 0.0f;
        if (t < IN) {
            const int sn = (s + 1 < SEQ) ? s + 1 : s;
            xnext = x[((size_t)sn * BATCH + b) * IN + t];
        }

        // ---- A: lin[t] = bias + W_ih[t,:]·x_t + W_hh[t,:]·h ----
        float lin = bias_t;
        {
            const float4* xs4 = (const float4*)x_sh[p];
            #pragma unroll
            for (int k = 0; k < IN / 4; ++k) {
                const float4 xv = xs4[k];
                lin += wi[k].x * xv.x + wi[k].y * xv.y + wi[k].z * xv.z + wi[k].w * xv.w;
            }
        }
        {
            const float4* hs4 = (const float4*)h_sh;
            #pragma unroll
            for (int k = 0; k < HID / 4; ++k) {
                const float4 hv = hs4[k];
                lin += wh[k].x * hv.x + wh[k].y * hv.y + wh[k].z * hv.z + wh[k].w * hv.w;
            }
        }
        lin_sh[t] = lin;
        __syncthreads();  // B: lin_sh complete

        // ---- C: gate combine (threads 0..255, one hidden unit each) ----
        if (t < HID) {
            const float li = lin_sh[t];
            const float lf = lin_sh[HID + t];
            const float lg = lin_sh[2 * HID + t];
            const float lo = lin_sh[3 * HID + t];
            const float ig = fsig(li);
            const float fg = fsig(lf);
            const float gg = ftanh(lg);
            const float og = fsig(lo);
            c = fg * c + ig * gg;
            h_sh[t] = og * ftanh(c);
        }
        if (t < IN) x_sh[p ^ 1][t] = xnext;
        __syncthreads();  // h_sh holds h_{s} (the scan output)

        // ---- D: fused readout out[s,b,o] = W_out[o,:]·h + b_out[o] ----
        float part = 0.0f;
        {
            const float4* hs4 = (const float4*)h_sh;
            #pragma unroll
            for (int q = 0; q < 4; ++q) {
                const float4 hv = hs4[seg * 4 + q];
                part += wo[q].x * hv.x + wo[q].y * hv.y + wo[q].z * hv.z + wo[q].w * hv.w;
            }
        }
        part += __shfl_xor(part, 1, 16);
        part += __shfl_xor(part, 2, 16);
        part += __shfl_xor(part, 4, 16);
        part += __shfl_xor(part, 8, 16);
        if (seg == 0) out[((size_t)s * BATCH + b) * OUTD + o] = part + bo;

        p ^= 1;
    }
}

extern "C" void kernel_launch(void* const* d_in, const int* in_sizes, int n_in,
                              void* d_out, int out_size, void* d_ws, size_t ws_size,
                              hipStream_t stream) {
    const float* x     = (const float*)d_in[0];
    const float* h0    = (const float*)d_in[1];
    const float* c0    = (const float*)d_in[2];
    const float* W_ih  = (const float*)d_in[3];
    const float* W_hh  = (const float*)d_in[4];
    const float* b     = (const float*)d_in[5];
    const float* W_out = (const float*)d_in[6];
    const float* b_out = (const float*)d_in[7];
    float* out = (float*)d_out;

    hipLaunchKernelGGL(lstm_persistent, dim3(BATCH), dim3(1024), 0, stream,
                       x, h0, c0, W_ih, W_hh, b, W_out, b_out, out);
}

// Round 2
// 8116.428 us; speedup vs baseline: 7.7504x; 7.7504x over previous
//
#include <hip/hip_runtime.h>
#include <cstdint>

#define SEQ   2048
#define BATCH 128
#define IN    64
#define HID   256
#define OUTD  64
#define G4    1024

#define T     512
#define NREG  22   // register chunks of 8 f16: k = 0..175
#define NLDS  3    // LDS chunks:               k = 176..199
#define NSTR  7    // streamed chunks:          k = 200..255
#define NIH   8    // W_ih chunks (64 inputs)

// ws layout in dwords
#define OFF_REG 0
#define SZ_REG  (2*NREG*512*4)        // 90112
#define OFF_LDS (OFF_REG+SZ_REG)      // 90112
#define SZ_LDS  (2*NLDS*512*4)        // 12288
#define OFF_STR (OFF_LDS+SZ_LDS)      // 102400
#define SZ_STR1 (2*NSTR*512*4)        // 28672 per copy (x2 copies: defeats load hoisting)
#define OFF_IH  (OFF_STR+2*SZ_STR1)   // 159744
#define SZ_IH1  (2*NIH*512*4)         // 32768 per copy (x2)
#define OFF_OUT (OFF_IH+2*SZ_IH1)     // 225280
#define SZ_OUT1 8192                  // dwords per copy (64*256 f16) (x2)
#define TOTAL_DW (OFF_OUT+2*SZ_OUT1)  // 241664 dwords = 966656 B of ws

typedef _Float16 f16x2 __attribute__((ext_vector_type(2)));

__device__ __forceinline__ float fexp2(float v) { return __builtin_amdgcn_exp2f(v); }
__device__ __forceinline__ float frcp(float v)  { return __builtin_amdgcn_rcpf(v); }
__device__ __forceinline__ float fsig(float v)  { return frcp(1.0f + fexp2(v * -1.44269504088896f)); }
__device__ __forceinline__ float ftanh_(float v){ return 1.0f - 2.0f * frcp(1.0f + fexp2(v * 2.88539008177793f)); }

__device__ __forceinline__ unsigned int pack2d(float a, float b) {
  unsigned short lo = __builtin_bit_cast(unsigned short, (_Float16)a);
  unsigned short hi = __builtin_bit_cast(unsigned short, (_Float16)b);
  return (unsigned int)lo | ((unsigned int)hi << 16);
}

__device__ __forceinline__ float dot2f(unsigned int w, unsigned int h, float acc) {
#if __has_builtin(__builtin_amdgcn_fdot2)
  return __builtin_amdgcn_fdot2(__builtin_bit_cast(f16x2, w), __builtin_bit_cast(f16x2, h), acc, false);
#else
  f16x2 a = __builtin_bit_cast(f16x2, w), b = __builtin_bit_cast(f16x2, h);
  return acc + (float)a.x * (float)b.x + (float)a.y * (float)b.y;
#endif
}

__device__ __forceinline__ void mac8(uint4 w, uint4 h, float& acc) {
  acc = dot2f(w.x, h.x, acc);
  acc = dot2f(w.y, h.y, acc);
  acc = dot2f(w.z, h.z, acc);
  acc = dot2f(w.w, h.w, acc);
}

// ---------------- prep: fp32 weights -> packed f16 layouts in ws ----------------
__global__ void prep_weights(const float* __restrict__ Whh, const float* __restrict__ Wih,
                             const float* __restrict__ Wout, unsigned int* __restrict__ ws) {
  int tid = blockIdx.x * 256 + threadIdx.x;
  if (tid >= TOTAL_DW) return;
  unsigned int val;
  if (tid < OFF_LDS) {                                   // register-resident W_hh part
    int q = tid & 3, t = (tid >> 2) & 511, rest = tid >> 11;
    int j = rest % NREG, s2 = rest / NREG;
    const float* p = Whh + (size_t)(s2*512 + t)*HID + 8*j + 2*q;
    val = pack2d(p[0], p[1]);
  } else if (tid < OFF_STR) {                            // LDS-resident W_hh part
    int r = tid - OFF_LDS;
    int q = r & 3, t = (r >> 2) & 511, rest = r >> 11;
    int j = rest % NLDS, s2 = rest / NLDS;
    const float* p = Whh + (size_t)(s2*512 + t)*HID + 176 + 8*j + 2*q;
    val = pack2d(p[0], p[1]);
  } else if (tid < OFF_IH) {                             // streamed W_hh tail (2 copies)
    int r = (tid - OFF_STR) % SZ_STR1;
    int q = r & 3, t = (r >> 2) & 511, rest = r >> 11;
    int j = rest % NSTR, s2 = rest / NSTR;
    const float* p = Whh + (size_t)(s2*512 + t)*HID + 200 + 8*j + 2*q;
    val = pack2d(p[0], p[1]);
  } else if (tid < OFF_OUT) {                            // W_ih (2 copies)
    int r = (tid - OFF_IH) % SZ_IH1;
    int q = r & 3, t = (r >> 2) & 511, rest = r >> 11;
    int j = rest & 7, s2 = rest >> 3;
    const float* p = Wih + (size_t)(s2*512 + t)*IN + 8*j + 2*q;
    val = pack2d(p[0], p[1]);
  } else {                                               // W_out (2 copies)
    int r = (tid - OFF_OUT) % SZ_OUT1;
    const float* p = Wout + 2*r;
    val = pack2d(p[0], p[1]);
  }
  ws[tid] = val;
}

// ---------------- main: one block per batch element ----------------
// Thread t owns gate-rows t and t+512. W_hh k=0..175 in 176 VGPRs (f16x2),
// k=176..199 in LDS, k=200..255 + W_ih + W_out streamed from L2 (shared by
// all 128 blocks, stays hot). h/x live in LDS as f16; dot via v_dot2_f32_f16.
__global__ __launch_bounds__(512, 2) void lstm_main(
    const float* __restrict__ x, const float* __restrict__ h0, const float* __restrict__ c0,
    const float* __restrict__ bias, const float* __restrict__ b_out,
    const unsigned int* __restrict__ wsbase, float* __restrict__ out)
{
  const int b = blockIdx.x, t = threadIdx.x;

  __shared__ __align__(16) unsigned int wlds[2*NLDS*512*4];   // 48 KiB
  __shared__ __align__(16) float lin_sh[G4];                  // 4 KiB
  __shared__ __align__(16) unsigned short hs[HID];            // h_t as f16
  __shared__ __align__(16) unsigned short xs[IN];             // x_t as f16

  const unsigned int* WregS = wsbase + OFF_REG;
  const unsigned int* WldsS = wsbase + OFF_LDS;
  const unsigned int* WstrS = wsbase + OFF_STR;
  const unsigned int* WihS  = wsbase + OFF_IH;
  const unsigned short* WoutS = (const unsigned short*)(wsbase + OFF_OUT);

  // persistent register weights
  uint4 wr0[NREG], wr1[NREG];
  #pragma unroll
  for (int j = 0; j < NREG; ++j) {
    wr0[j] = *(const uint4*)(WregS + ((size_t)(0*NREG + j)*512 + t)*4);
    wr1[j] = *(const uint4*)(WregS + ((size_t)(1*NREG + j)*512 + t)*4);
  }
  // LDS weight slice
  #pragma unroll
  for (int v = 0; v < 2*NLDS; ++v) {
    int idx = (v*512 + t)*4;
    *(uint4*)(wlds + idx) = *(const uint4*)(WldsS + idx);
  }

  float c = 0.0f;
  if (t < HID) {
    c = c0[(size_t)b*HID + t];
    hs[t] = (unsigned short)(pack2d(h0[(size_t)b*HID + t], 0.0f) & 0xffffu);
  } else if (t < HID + 32) {
    int i = t - HID;
    float2 xx = *(const float2*)(x + (size_t)b*IN + 2*i);   // x at s=0
    ((unsigned int*)xs)[i] = pack2d(xx.x, xx.y);
  }
  const float bz0 = bias[t], bz1 = bias[t + 512];
  const float bo  = b_out[t >> 3];
  __syncthreads();

  for (int s = 0; s < SEQ; ++s) {
    // prefetch next step's x (threads 256..287)
    float2 xn = make_float2(0.0f, 0.0f);
    if (t >= HID && t < HID + 32) {
      int sn = (s + 1 < SEQ) ? s + 1 : s;
      xn = *(const float2*)(x + ((size_t)sn*BATCH + b)*IN + 2*(t - HID));
    }
    const int alt = s & 1;                       // alternate ws copies: defeats hoisting
    const unsigned int* strB = WstrS + (size_t)alt*SZ_STR1;
    const unsigned int* ihB  = WihS  + (size_t)alt*SZ_IH1;
    const unsigned short* woB = WoutS + (size_t)alt*(2*SZ_OUT1);

    float lin0 = bz0, lin1 = bz1;
    // register part (k = 0..175); h chunks broadcast from LDS
    #pragma unroll
    for (int j = 0; j < NREG; ++j) {
      uint4 hv = *(const uint4*)(hs + 8*j);
      mac8(wr0[j], hv, lin0);
      mac8(wr1[j], hv, lin1);
    }
    // LDS part (k = 176..199)
    #pragma unroll
    for (int j = 0; j < NLDS; ++j) {
      uint4 hv = *(const uint4*)(hs + 176 + 8*j);
      uint4 w0 = *(const uint4*)(wlds + ((0*NLDS + j)*512 + t)*4);
      uint4 w1 = *(const uint4*)(wlds + ((1*NLDS + j)*512 + t)*4);
      mac8(w0, hv, lin0);
      mac8(w1, hv, lin1);
    }
    // streamed W_hh tail (k = 200..255)
    #pragma unroll
    for (int j = 0; j < NSTR; ++j) {
      uint4 hv = *(const uint4*)(hs + 200 + 8*j);
      uint4 w0 = *(const uint4*)(strB + ((size_t)(0*NSTR + j)*512 + t)*4);
      uint4 w1 = *(const uint4*)(strB + ((size_t)(1*NSTR + j)*512 + t)*4);
      mac8(w0, hv, lin0);
      mac8(w1, hv, lin1);
    }
    // x projection (streamed W_ih)
    #pragma unroll
    for (int j = 0; j < NIH; ++j) {
      uint4 xv = *(const uint4*)(xs + 8*j);
      uint4 w0 = *(const uint4*)(ihB + ((size_t)(0*NIH + j)*512 + t)*4);
      uint4 w1 = *(const uint4*)(ihB + ((size_t)(1*NIH + j)*512 + t)*4);
      mac8(w0, xv, lin0);
      mac8(w1, xv, lin1);
    }
    lin_sh[t]       = lin0;
    lin_sh[t + 512] = lin1;

    // issue W_out loads early (consumed after barrier b)
    const int o = t >> 3, seg = t & 7;
    uint4 wo[4];
    #pragma unroll
    for (int q = 0; q < 4; ++q)
      wo[q] = *(const uint4*)(woB + (size_t)o*256 + seg*32 + 8*q);

    __syncthreads();  // (a) lin complete

    if (t < HID) {
      float li  = lin_sh[t];
      float lf  = lin_sh[t + 256];
      float lg  = lin_sh[t + 512];
      float lo_ = lin_sh[t + 768];
      float ig = fsig(li), fg = fsig(lf), gg = ftanh_(lg), og = fsig(lo_);
      c = fg*c + ig*gg;
      float hn = og*ftanh_(c);
      hs[t] = (unsigned short)(pack2d(hn, 0.0f) & 0xffffu);
    } else if (t < HID + 32) {
      ((unsigned int*)xs)[t - HID] = pack2d(xn.x, xn.y);
    }
    __syncthreads();  // (b) h_s / x_{s+1} published

    // fused readout: out[s,b,o] = W_out[o,:]·h_s + b_out[o]
    float acc = 0.0f;
    #pragma unroll
    for (int q = 0; q < 4; ++q) {
      uint4 hv = *(const uint4*)(hs + seg*32 + 8*q);
      mac8(wo[q], hv, acc);
    }
    acc += __shfl_xor(acc, 1);
    acc += __shfl_xor(acc, 2);
    acc += __shfl_xor(acc, 4);
    if (seg == 0) out[((size_t)s*BATCH + b)*OUTD + o] = acc + bo;
  }
}

extern "C" void kernel_launch(void* const* d_in, const int* in_sizes, int n_in,
                              void* d_out, int out_size, void* d_ws, size_t ws_size,
                              hipStream_t stream) {
  const float* x     = (const float*)d_in[0];
  const float* h0    = (const float*)d_in[1];
  const float* c0    = (const float*)d_in[2];
  const float* W_ih  = (const float*)d_in[3];
  const float* W_hh  = (const float*)d_in[4];
  const float* bias  = (const float*)d_in[5];
  const float* W_out = (const float*)d_in[6];
  const float* b_out = (const float*)d_in[7];
  float* out = (float*)d_out;
  unsigned int* ws = (unsigned int*)d_ws;

  hipLaunchKernelGGL(prep_weights, dim3((TOTAL_DW + 255)/256), dim3(256), 0, stream,
                     W_hh, W_ih, W_out, ws);
  hipLaunchKernelGGL(lstm_main, dim3(BATCH), dim3(T), 0, stream,
                     x, h0, c0, bias, b_out, ws, out);
}